// Round 4
// baseline (72.942 us; speedup 1.0000x reference)
//
#include <hip/hip_runtime.h>

// Max-unpool 2x2: x[B=16,H=128,W=128,C=64] f32, indices int32 encoding
// per-batch flat position ((2h+dy)*Wout + (2w+dx))*C + c in output
// [B,Hout=256,Wout=256,C=64]. Each input element lands in its own disjoint
// 2x2 window -> no collisions. One thread owns one window x 4 channels:
// 4 float4 stores (value where idx matches, else zero). Covers every output
// element exactly once -> no zero-init pass, no atomics.
//
// R1: nontemporal loads/stores (pure streaming, 448 MB vs 32 MB L2). 80->70.7us.
// R3: grid-stride with capped grid (2048 blocks) + 2x unroll: fewer short-lived
//     blocks, 4 independent loads in flight per iteration (deeper MLP).

typedef float f32x4 __attribute__((ext_vector_type(4)));
typedef int   i32x4 __attribute__((ext_vector_type(4)));

__device__ __forceinline__ void unpool_one(f32x4* __restrict__ out, int t,
                                           f32x4 v, i32x4 id)
{
    int e = t << 2;              // first element index (4 consecutive channels)
    int c = e & 63;              // channel (multiple of 4)
    int w = (e >> 6)  & 127;
    int h = (e >> 13) & 127;
    int b =  e >> 20;

    // within-batch output element offset of (row=2h, col=2w, chan=c)
    int pos00 = (h << 15) | (w << 7) | c;
    size_t base = ((size_t)b << 22) + (size_t)pos00;  // Hout*Wout*C = 1<<22

    i32x4 cc = {pos00 + 0, pos00 + 1, pos00 + 2, pos00 + 3};

    f32x4 s00, s01, s10, s11;
    s00.x = (id.x == cc.x) ? v.x : 0.0f;
    s00.y = (id.y == cc.y) ? v.y : 0.0f;
    s00.z = (id.z == cc.z) ? v.z : 0.0f;
    s00.w = (id.w == cc.w) ? v.w : 0.0f;

    s01.x = (id.x == cc.x + 64) ? v.x : 0.0f;
    s01.y = (id.y == cc.y + 64) ? v.y : 0.0f;
    s01.z = (id.z == cc.z + 64) ? v.z : 0.0f;
    s01.w = (id.w == cc.w + 64) ? v.w : 0.0f;

    s10.x = (id.x == cc.x + 16384) ? v.x : 0.0f;
    s10.y = (id.y == cc.y + 16384) ? v.y : 0.0f;
    s10.z = (id.z == cc.z + 16384) ? v.z : 0.0f;
    s10.w = (id.w == cc.w + 16384) ? v.w : 0.0f;

    s11.x = (id.x == cc.x + 16448) ? v.x : 0.0f;
    s11.y = (id.y == cc.y + 16448) ? v.y : 0.0f;
    s11.z = (id.z == cc.z + 16448) ? v.z : 0.0f;
    s11.w = (id.w == cc.w + 16448) ? v.w : 0.0f;

    f32x4* o = out + (base >> 2);
    __builtin_nontemporal_store(s00, &o[0]);     // (2h,   2w  , c..c+3)
    __builtin_nontemporal_store(s01, &o[16]);    // +64 floats
    __builtin_nontemporal_store(s10, &o[4096]);  // +16384 floats
    __builtin_nontemporal_store(s11, &o[4112]);
}

__global__ __launch_bounds__(256) void unpool_window_kernel(
    const f32x4* __restrict__ x,
    const i32x4* __restrict__ ind,
    f32x4*       __restrict__ out,
    int nvec)
{
    int t      = blockIdx.x * blockDim.x + threadIdx.x;
    int stride = gridDim.x * blockDim.x;

    for (int i = t; i < nvec; i += 2 * stride) {
        int j = i + stride;
        // issue all independent loads first (4 in flight)
        f32x4 v0 = __builtin_nontemporal_load(&x[i]);
        i32x4 d0 = __builtin_nontemporal_load(&ind[i]);
        f32x4 v1;
        i32x4 d1;
        bool hj = (j < nvec);
        if (hj) {
            v1 = __builtin_nontemporal_load(&x[j]);
            d1 = __builtin_nontemporal_load(&ind[j]);
        }
        unpool_one(out, i, v0, d0);
        if (hj) unpool_one(out, j, v1, d1);
    }
}

extern "C" void kernel_launch(void* const* d_in, const int* in_sizes, int n_in,
                              void* d_out, int out_size, void* d_ws, size_t ws_size,
                              hipStream_t stream) {
    const f32x4* x   = (const f32x4*)d_in[0];
    const i32x4* ind = (const i32x4*)d_in[1];
    f32x4*       out = (f32x4*)d_out;

    int n_elems = in_sizes[0];          // B*H*W*C = 16,777,216
    int nvec    = n_elems >> 2;         // 4,194,304 vec4 elements
    int block   = 256;
    int grid    = 2048;                 // 256 CU x 8 blocks/CU; grid-stride x8

    unpool_window_kernel<<<grid, block, 0, stream>>>(x, ind, out, nvec);
}

// Round 5
// 64.199 us; speedup vs baseline: 1.1362x; 1.1362x over previous
//
#include <hip/hip_runtime.h>

// Max-unpool 2x2, OUTPUT-centric (R4): each thread owns one output vec4
// (b,ho,wo,c..c+3) of out[B=16,Hout=256,Wout=256,C=64]. It reads the unique
// input vec4 (b,ho/2,wo/2,c..c+3) + its indices, and writes x where the
// stored index equals this output position, else 0. Wave stores are 1KB
// fully contiguous (vs 256B@512B-stride segments in the window-centric R2).
// Reads are CACHED (L1/L2 serve the 4x positional reuse: lane-pair dups in
// the same instruction, row-pair reuse within L2); stores are nontemporal
// (256 MB pure stream, no reuse).
//
// History: R2 window-centric + nt everywhere = 70.7us (5.70 TB/s eff).
// R3 grid-stride cap = 72.9us (regressed, reverted).

typedef float f32x4 __attribute__((ext_vector_type(4)));
typedef int   i32x4 __attribute__((ext_vector_type(4)));

__global__ __launch_bounds__(256) void unpool_out_kernel(
    const f32x4* __restrict__ x,
    const i32x4* __restrict__ ind,
    f32x4*       __restrict__ out,
    int novec)
{
    int o = blockIdx.x * blockDim.x + threadIdx.x;   // output vec4 index
    if (o >= novec) return;

    // out layout [B,256,256,16 vec4s]: c4 = o&15, wo = (o>>4)&255,
    // ho = (o>>12)&255, b = o>>20
    int c4 = o & 15;
    int wo = (o >> 4)  & 255;
    int ho = (o >> 12) & 255;
    int b  =  o >> 20;

    // input vec4 index: ((b*128 + ho/2)*128 + wo/2)*16 + c4
    int in_vec = (b << 18) | ((ho >> 1) << 11) | ((wo >> 1) << 4) | c4;

    f32x4 v  = x[in_vec];     // cached: 4x positional reuse via L1/L2
    i32x4 id = ind[in_vec];

    // expected per-batch flat element position of this output vec4
    int pos = (ho << 14) | (wo << 6) | (c4 << 2);

    f32x4 s;
    s.x = (id.x == pos + 0) ? v.x : 0.0f;
    s.y = (id.y == pos + 1) ? v.y : 0.0f;
    s.z = (id.z == pos + 2) ? v.z : 0.0f;
    s.w = (id.w == pos + 3) ? v.w : 0.0f;

    __builtin_nontemporal_store(s, &out[o]);
}

extern "C" void kernel_launch(void* const* d_in, const int* in_sizes, int n_in,
                              void* d_out, int out_size, void* d_ws, size_t ws_size,
                              hipStream_t stream) {
    const f32x4* x   = (const f32x4*)d_in[0];
    const i32x4* ind = (const i32x4*)d_in[1];
    f32x4*       out = (f32x4*)d_out;

    int novec = out_size >> 2;          // B*Hout*Wout*C/4 = 16,777,216 vec4s
    int block = 256;
    int grid  = (novec + block - 1) / block;   // 65536

    unpool_out_kernel<<<grid, block, 0, stream>>>(x, ind, out, novec);
}